// Round 7
// baseline (435.529 us; speedup 1.0000x reference)
//
#include <hip/hip_runtime.h>

// DecoderLayer (eval): SA(causal) -> +res -> LN1 -> CA -> +res -> LN2 -> FFN -> +res -> LN3
// Round-5 kernel, third submission (rounds 5 and 6 both lost to GPU acquisition
// timeouts — never benched). Unchanged for clean attribution:
//  - Attention: VALU surgery. v_cvt_pk_bf16_f32 for P-pack (was ~8-instr manual pack),
//    HW exp2 (__builtin_amdgcn_exp2f), defer-max THR=8 (skip O-rescale + broadcasts
//    unless tile max grows >8; LSE combine stays exact).
//  - GEMM: generic BM x BN template; 128x128 (m97 structure) for QKV/CKV/FFN1,
//    128x64 for all N=512 GEMMs (grid >= 256 blocks everywhere).
//  - Unchanged: KV-split(4) flash + LSE combine, exp2-domain softmax (scale folded
//    into Q), LN-stats refusion epilogues, bf16 weights pre-transposed.

#define D_MODEL 512
#define NHEAD 8
#define DK 64
#define SEQ 2048
#define MTOK 4096
#define DFF 2048

typedef __attribute__((ext_vector_type(8))) short bf16x8;
typedef __attribute__((ext_vector_type(4))) float f32x4;

#if __has_builtin(__builtin_amdgcn_exp2f)
#define EXP2(x) __builtin_amdgcn_exp2f(x)
#else
#define EXP2(x) exp2f(x)
#endif

__device__ __forceinline__ unsigned short f2bf(float x) {  // RTN-even
  unsigned u = __float_as_uint(x);
  u += 0x7FFF + ((u >> 16) & 1);
  return (unsigned short)(u >> 16);
}
__device__ __forceinline__ unsigned pack2(float a, float b) {
  return (unsigned)f2bf(a) | ((unsigned)f2bf(b) << 16);
}
__device__ __forceinline__ unsigned cvtpk(float lo, float hi) {  // RNE, 1 instr
  unsigned r;
  asm("v_cvt_pk_bf16_f32 %0, %1, %2" : "=v"(r) : "v"(lo), "v"(hi));
  return r;
}
__device__ __forceinline__ void load_lds16(const unsigned short* g, unsigned short* l) {
  __builtin_amdgcn_global_load_lds(
      (const __attribute__((address_space(1))) void*)g,
      (__attribute__((address_space(3))) void*)l, 16, 0, 0);
}

// ---------------------------------------------------------------------------
// Weight prep: fp32 [K][N] -> bf16 [N][K] (transpose + cast). Concat via dst offsets.
struct WDesc { const float* src; unsigned short* dst; int K; int N; };
struct WPack { WDesc d[10]; };

__global__ __launch_bounds__(256)
void wprep_kernel(WPack p) {
  const WDesc wd = p.d[blockIdx.y];
  const int ntx = wd.N >> 5;
  const int ntile = (wd.K >> 5) * ntx;
  if ((int)blockIdx.x >= ntile) return;
  const int n0 = (blockIdx.x % ntx) * 32;
  const int k0 = (blockIdx.x / ntx) * 32;
  __shared__ float T[32][33];
  const int tid = threadIdx.x;
  {
    const int r = tid >> 3, c4 = (tid & 7) * 4;
    float4 v = *(const float4*)(wd.src + (long)(k0 + r) * wd.N + n0 + c4);
    T[r][c4] = v.x; T[r][c4 + 1] = v.y; T[r][c4 + 2] = v.z; T[r][c4 + 3] = v.w;
  }
  __syncthreads();
  {
    const int n = tid >> 3, kq = (tid & 7) * 4;
    ushort4 o;
    o.x = f2bf(T[kq + 0][n]); o.y = f2bf(T[kq + 1][n]);
    o.z = f2bf(T[kq + 2][n]); o.w = f2bf(T[kq + 3][n]);
    *(ushort4*)(wd.dst + (long)(n0 + n) * wd.K + k0 + kq) = o;
  }
}

__global__ __launch_bounds__(256)
void cast_kernel(const float* __restrict__ s, unsigned short* __restrict__ d, int n8) {
  const int i = blockIdx.x * 256 + threadIdx.x;
  if (i >= n8) return;
  float4 a = *(const float4*)(s + (long)i * 8);
  float4 b = *(const float4*)(s + (long)i * 8 + 4);
  uint4 o;
  o.x = pack2(a.x, a.y); o.y = pack2(a.z, a.w);
  o.z = pack2(b.x, b.y); o.w = pack2(b.z, b.w);
  *(uint4*)(d + (long)i * 8) = o;
}

// ---------------------------------------------------------------------------
// bf16 MFMA GEMM, tile BM x BN, BK=32, 4 waves (2x2), wave tile (BM/2)x(BN/2).
// MODE 0: head-split bf16 out to o{0,1,2} by c>>9, bias b{0,1,2}[c&511], *scale0 on o0.
// MODE 1: fp32 out of = acc + b0[c] + res[r,c].
// MODE 2: bf16 out o0 = relu(acc + b0[c]).
// MODE 3: fp32 out of = acc + b0[c] + LN(res[r,c]; lnm,lnr,lng,lnbt)   (of may alias res).
template<int MODE, int BM, int BN>
__global__ __launch_bounds__(256)
void gemm_bf16(const unsigned short* __restrict__ A, const unsigned short* __restrict__ Wt,
               const float* __restrict__ b0, const float* __restrict__ b1,
               const float* __restrict__ b2, const float* res,
               const float* __restrict__ lnm, const float* __restrict__ lnr,
               const float* __restrict__ lng, const float* __restrict__ lnbt,
               unsigned short* __restrict__ o0, unsigned short* __restrict__ o1,
               unsigned short* __restrict__ o2, float* of,
               int M, int N, int K, float scale0) {
  constexpr int MF = BM / 32, NF = BN / 32;
  constexpr int AI = BM / 64, BI = BN / 64;
  __shared__ unsigned short As[BM * 32];  // [kg4][mBM][8]
  __shared__ unsigned short Bs[BN * 32];  // [kg4][nBN][8]
  const int tid = threadIdx.x;
  const int w = tid >> 6, lane = tid & 63, g = lane >> 4, li = lane & 15;
  const int m0 = blockIdx.x * BM, n0 = blockIdx.y * BN;
  const int wm = w >> 1, wn = w & 1;

  f32x4 acc[MF][NF] = {};
  const unsigned short* Ap[AI];
  const unsigned short* Bp[BI];
#pragma unroll
  for (int i = 0; i < AI; i++) {
    const int idx = i * 256 + tid;
    Ap[i] = A + (long)(m0 + (idx % BM)) * K + (idx / BM) * 8;
  }
#pragma unroll
  for (int i = 0; i < BI; i++) {
    const int idx = i * 256 + tid;
    Bp[i] = Wt + (long)(n0 + (idx % BN)) * K + (idx / BN) * 8;
  }

  for (int k0 = 0; k0 < K; k0 += 32) {
    __syncthreads();
#pragma unroll
    for (int i = 0; i < AI; i++) load_lds16(Ap[i] + k0, &As[(i * 256 + w * 64) * 8]);
#pragma unroll
    for (int i = 0; i < BI; i++) load_lds16(Bp[i] + k0, &Bs[(i * 256 + w * 64) * 8]);
    __syncthreads();
    bf16x8 af[MF], bfr[NF];
#pragma unroll
    for (int mf = 0; mf < MF; mf++)
      af[mf] = *(const bf16x8*)&As[(g * BM + wm * (BM / 2) + mf * 16 + li) * 8];
#pragma unroll
    for (int nf = 0; nf < NF; nf++)
      bfr[nf] = *(const bf16x8*)&Bs[(g * BN + wn * (BN / 2) + nf * 16 + li) * 8];
#pragma unroll
    for (int mf = 0; mf < MF; mf++)
#pragma unroll
      for (int nf = 0; nf < NF; nf++)
        acc[mf][nf] = __builtin_amdgcn_mfma_f32_16x16x32_bf16(af[mf], bfr[nf], acc[mf][nf], 0, 0, 0);
  }

#pragma unroll
  for (int nf = 0; nf < NF; nf++) {
    const int c = n0 + wn * (BN / 2) + nf * 16 + li;
    float bias, scl = 1.f;
    unsigned short* hdst = nullptr;
    float lngv = 0.f, lnbv = 0.f;
    if constexpr (MODE == 0) {
      const int which = c >> 9;
      bias = (which == 0 ? b0 : (which == 1 ? b1 : b2))[c & 511];
      if (which == 0) scl = scale0;
      hdst = which == 0 ? o0 : (which == 1 ? o1 : o2);
    } else {
      bias = b0[c];
      if constexpr (MODE == 3) { lngv = lng[c]; lnbv = lnbt[c]; }
    }
#pragma unroll
    for (int mf = 0; mf < MF; mf++) {
#pragma unroll
      for (int j = 0; j < 4; j++) {
        const int r = m0 + wm * (BM / 2) + mf * 16 + g * 4 + j;
        float v = acc[mf][nf][j] + bias;
        if constexpr (MODE == 0) {
          v *= scl;
          const int b = r >> 11, s = r & (SEQ - 1), h = (c >> 6) & 7, d = c & 63;
          hdst[(((long)(b * NHEAD + h)) * SEQ + s) * DK + d] = f2bf(v);
        } else if constexpr (MODE == 1) {
          v += res[(long)r * N + c];
          of[(long)r * N + c] = v;
        } else if constexpr (MODE == 2) {
          o0[(long)r * N + c] = f2bf(fmaxf(v, 0.f));
        } else {
          const float xr = res[(long)r * N + c];
          v += (xr - lnm[r]) * lnr[r] * lngv + lnbv;
          of[(long)r * N + c] = v;
        }
      }
    }
  }
}

// ---------------------------------------------------------------------------
// Flash attention chunk, bf16 MFMA. Q pre-scaled by 0.125*log2e (exp2 domain).
// Grid (SEQ/128, B*NHEAD, 4). Writes unnormalized fp32 O + (m,l) per chunk.
template<bool CAUSAL>
__global__ __launch_bounds__(256)
void attn_bf16(const unsigned short* __restrict__ Qg, const unsigned short* __restrict__ Kg,
               const unsigned short* __restrict__ Vg, float* __restrict__ Opart,
               float* __restrict__ Mst, float* __restrict__ Lst) {
  __shared__ unsigned short SM[16384];   // 32KB
  unsigned short* const Qp = SM;         // [dg8][q128][8]  (dead after bq load)
  unsigned short* const Kp = SM + 8192;  // [dg8][k64][8]
  unsigned short* const Vt = SM + 12288; // [sg8][d64^swz][8]
  const int tid = threadIdx.x;
  const int w = tid >> 6, lane = tid & 63, g = lane >> 4, li = lane & 15;
  const int qb = blockIdx.x, bh = blockIdx.y, ck = blockIdx.z;
  const int q0 = qb * 128;
  const long base = (long)bh * SEQ * DK;
  unsigned short* const Pl = SM + w * 2048;  // aliases Qp region (per-wave)

#pragma unroll
  for (int i = 0; i < 4; i++) {
    const int idx = i * 256 + tid;
    const int dg = idx >> 7, q = idx & 127;
    load_lds16(Qg + base + (long)(q0 + q) * DK + dg * 8, &Qp[(i * 256 + w * 64) * 8]);
  }
  __syncthreads();
  bf16x8 bq[2][2];
#pragma unroll
  for (int qf = 0; qf < 2; qf++)
#pragma unroll
    for (int ks = 0; ks < 2; ks++)
      bq[qf][ks] = *(const bf16x8*)&Qp[((ks * 4 + g) * 128 + w * 32 + qf * 16 + li) * 8];

  f32x4 oacc[2][4] = {};
  float mrun[2] = {-1e30f, -1e30f};
  float denom[2] = {0.f, 0.f};

  const int vdg = tid >> 5;
  const int vs0 = (tid & 31) * 2;
  const int vsg = vs0 >> 3, vso = vs0 & 7;

  const int tbeg = CAUSAL ? ck : ck * 8;
  const int tend = CAUSAL ? (2 * qb + 2) : (ck * 8 + 8);
  const int tstep = CAUSAL ? 4 : 1;
  for (int t = tbeg; t < tend; t += tstep) {
    const int k0 = t * 64;
    __syncthreads();
#pragma unroll
    for (int i = 0; i < 2; i++) {
      const int idx = i * 256 + tid;
      const int dg = idx >> 6, kk = idx & 63;
      load_lds16(Kg + base + (long)(k0 + kk) * DK + dg * 8, &Kp[(i * 256 + w * 64) * 8]);
    }
    {
      const unsigned short* vsrc = Vg + base + (long)(k0 + vs0) * DK + vdg * 8;
      uint4 r0 = *(const uint4*)vsrc;
      uint4 r1 = *(const uint4*)(vsrc + DK);
      unsigned short u0[8], u1[8];
      *(uint4*)u0 = r0; *(uint4*)u1 = r1;
#pragma unroll
      for (int e = 0; e < 8; e++) {
        const int d = vdg * 8 + e;
        const int dsw = d ^ (vsg & 7);
        *(unsigned*)&Vt[(vsg * 64 + dsw) * 8 + vso] =
            (unsigned)u0[e] | ((unsigned)u1[e] << 16);
      }
    }
    __syncthreads();

    // S^T = K * Q^T (exp2 domain; Q pre-scaled)
    f32x4 sacc[4][2] = {};
#pragma unroll
    for (int ks = 0; ks < 2; ks++) {
#pragma unroll
      for (int kf = 0; kf < 4; kf++) {
        bf16x8 ka = *(const bf16x8*)&Kp[((ks * 4 + g) * 64 + kf * 16 + li) * 8];
#pragma unroll
        for (int qf = 0; qf < 2; qf++)
          sacc[kf][qf] = __builtin_amdgcn_mfma_f32_16x16x32_bf16(ka, bq[qf][ks], sacc[kf][qf], 0, 0, 0);
      }
    }
    if (CAUSAL && t >= 2 * qb) {
#pragma unroll
      for (int kf = 0; kf < 4; kf++)
#pragma unroll
        for (int qf = 0; qf < 2; qf++)
#pragma unroll
          for (int j = 0; j < 4; j++) {
            const int kg_ = k0 + kf * 16 + g * 4 + j;
            const int qg_ = q0 + w * 32 + qf * 16 + li;
            if (kg_ > qg_) sacc[kf][qf][j] = -1e30f;
          }
    }
    // tile max per q-row (replicated across the 4 g-groups of each li)
    float mx[2];
#pragma unroll
    for (int qf = 0; qf < 2; qf++) {
      float a = fmaxf(fmaxf(sacc[0][qf][0], sacc[0][qf][1]), fmaxf(sacc[0][qf][2], sacc[0][qf][3]));
      float b = fmaxf(fmaxf(sacc[1][qf][0], sacc[1][qf][1]), fmaxf(sacc[1][qf][2], sacc[1][qf][3]));
      float c = fmaxf(fmaxf(sacc[2][qf][0], sacc[2][qf][1]), fmaxf(sacc[2][qf][2], sacc[2][qf][3]));
      float d = fmaxf(fmaxf(sacc[3][qf][0], sacc[3][qf][1]), fmaxf(sacc[3][qf][2], sacc[3][qf][3]));
      float m_ = fmaxf(fmaxf(a, b), fmaxf(c, d));
      m_ = fmaxf(m_, __shfl_xor(m_, 16, 64));
      m_ = fmaxf(m_, __shfl_xor(m_, 32, 64));
      mx[qf] = m_;
    }
    // defer-max: only pay rescale when a row max grew by >8 (exp2-domain)
    const int full = !__all((mx[0] - mrun[0] <= 8.f) && (mx[1] - mrun[1] <= 8.f));
    float corrv[2] = {1.f, 1.f};
    if (full) {
#pragma unroll
      for (int qf = 0; qf < 2; qf++) {
        const float mn = fmaxf(mrun[qf], mx[qf]);
        corrv[qf] = EXP2(mrun[qf] - mn);
        mrun[qf] = mn;
      }
    }
#pragma unroll
    for (int qf = 0; qf < 2; qf++) {
      float ps = 0.f;
#pragma unroll
      for (int kf = 0; kf < 4; kf++)
#pragma unroll
        for (int j = 0; j < 4; j++) {
          const float p = EXP2(sacc[kf][qf][j] - mrun[qf]);
          sacc[kf][qf][j] = p;
          ps += p;
        }
      ps += __shfl_xor(ps, 16, 64);
      ps += __shfl_xor(ps, 32, 64);
      denom[qf] = denom[qf] * corrv[qf] + ps;
    }
    if (full) {
#pragma unroll
      for (int mf = 0; mf < 2; mf++)
#pragma unroll
        for (int j = 0; j < 4; j++) {
          const float cf = __shfl(corrv[mf], g * 4 + j, 64);
#pragma unroll
          for (int df = 0; df < 4; df++) oacc[mf][df][j] *= cf;
        }
    }
    // P -> LDS (bf16, v_cvt_pk)
#pragma unroll
    for (int kf = 0; kf < 4; kf++)
#pragma unroll
      for (int qf = 0; qf < 2; qf++) {
        uint2 pv;
        pv.x = cvtpk(sacc[kf][qf][0], sacc[kf][qf][1]);
        pv.y = cvtpk(sacc[kf][qf][2], sacc[kf][qf][3]);
        *(uint2*)&Pl[((kf * 2 + (g >> 1)) * 32 + qf * 16 + li) * 8 + (g & 1) * 4] = pv;
      }
#pragma unroll
    for (int ks2 = 0; ks2 < 2; ks2++) {
      const int sg = ks2 * 4 + g;
#pragma unroll
      for (int mf = 0; mf < 2; mf++) {
        bf16x8 pa = *(const bf16x8*)&Pl[(sg * 32 + mf * 16 + li) * 8];
#pragma unroll
        for (int df = 0; df < 4; df++) {
          bf16x8 vb = *(const bf16x8*)&Vt[(sg * 64 + ((df * 16 + li) ^ (sg & 7))) * 8];
          oacc[mf][df] = __builtin_amdgcn_mfma_f32_16x16x32_bf16(pa, vb, oacc[mf][df], 0, 0, 0);
        }
      }
    }
  }

  // unnormalized partial + stats
  const long pbase = (long)(ck * 16 + bh) * SEQ;
  if (g == 0) {
#pragma unroll
    for (int qf = 0; qf < 2; qf++) {
      const int q = q0 + w * 32 + qf * 16 + li;
      Mst[pbase + q] = mrun[qf];
      Lst[pbase + q] = denom[qf];
    }
  }
#pragma unroll
  for (int mf = 0; mf < 2; mf++)
#pragma unroll
    for (int j = 0; j < 4; j++) {
      const int q = q0 + w * 32 + mf * 16 + g * 4 + j;
      float* op = Opart + (pbase + q) * 64;
#pragma unroll
      for (int df = 0; df < 4; df++) op[df * 16 + li] = oacc[mf][df][j];
    }
}

// ---------------------------------------------------------------------------
// LSE combine over 4 chunks -> AOb bf16 [B,S,D_MODEL]. One wave per q row.
__global__ __launch_bounds__(256)
void combine_kernel(const float* __restrict__ Opart, const float* __restrict__ Mst,
                    const float* __restrict__ Lst, unsigned short* __restrict__ AOb) {
  const int row = blockIdx.x * 4 + (threadIdx.x >> 6);  // bh*SEQ + q
  const int lane = threadIdx.x & 63;
  const int bh = row >> 11, q = row & (SEQ - 1);
  float m[4], l[4], mstar = -1e30f;
#pragma unroll
  for (int c = 0; c < 4; c++) {
    m[c] = Mst[((long)c * 16 + bh) * SEQ + q];
    l[c] = Lst[((long)c * 16 + bh) * SEQ + q];
    mstar = fmaxf(mstar, m[c]);
  }
  float den = 0.f, o = 0.f;
#pragma unroll
  for (int c = 0; c < 4; c++) {
    const float wgt = EXP2(m[c] - mstar);
    den += wgt * l[c];
    o += wgt * Opart[(((long)c * 16 + bh) * SEQ + q) * 64 + lane];
  }
  const int b = bh >> 3, h = bh & 7;
  AOb[((long)(b * SEQ + q)) * D_MODEL + h * DK + lane] = f2bf(o / den);
}

// ---------------------------------------------------------------------------
// LayerNorm (512). V0: bf16 out + (mu,rstd) stats. V1: fp32 out.
template<int V>
__global__ __launch_bounds__(256)
void ln_kernel(const float* __restrict__ x, const float* __restrict__ gam,
               const float* __restrict__ bet, float* __restrict__ outf,
               unsigned short* __restrict__ outb, float* __restrict__ mu_s,
               float* __restrict__ rs_s) {
  const int row = blockIdx.x * 4 + (threadIdx.x >> 6);
  const int lane = threadIdx.x & 63;
  const float* xr = x + (long)row * D_MODEL;
  float4 v0 = *(const float4*)&xr[lane * 8];
  float4 v1 = *(const float4*)&xr[lane * 8 + 4];
  float xv[8] = {v0.x, v0.y, v0.z, v0.w, v1.x, v1.y, v1.z, v1.w};
  float s = 0.f, s2 = 0.f;
#pragma unroll
  for (int i = 0; i < 8; i++) { s += xv[i]; s2 = fmaf(xv[i], xv[i], s2); }
#pragma unroll
  for (int off = 32; off > 0; off >>= 1) {
    s += __shfl_xor(s, off, 64);
    s2 += __shfl_xor(s2, off, 64);
  }
  const float mu = s * (1.f / D_MODEL);
  const float var = fmaxf(s2 * (1.f / D_MODEL) - mu * mu, 0.f);
  const float rstd = rsqrtf(var + 1e-5f);
  float y[8];
#pragma unroll
  for (int i = 0; i < 8; i++) {
    const int c = lane * 8 + i;
    y[i] = (xv[i] - mu) * rstd * gam[c] + bet[c];
  }
  if constexpr (V == 0) {
    uint4 o;
    o.x = pack2(y[0], y[1]); o.y = pack2(y[2], y[3]);
    o.z = pack2(y[4], y[5]); o.w = pack2(y[6], y[7]);
    *(uint4*)(outb + (long)row * D_MODEL + lane * 8) = o;
    if (lane == 0) { mu_s[row] = mu; rs_s[row] = rstd; }
  } else {
    float* orow = outf + (long)row * D_MODEL + lane * 8;
    *(float4*)orow = make_float4(y[0], y[1], y[2], y[3]);
    *(float4*)(orow + 4) = make_float4(y[4], y[5], y[6], y[7]);
  }
}

// ---------------------------------------------------------------------------
extern "C" void kernel_launch(void* const* d_in, const int* in_sizes, int n_in,
                              void* d_out, int out_size, void* d_ws, size_t ws_size,
                              hipStream_t stream) {
  const float* dec = (const float*)d_in[0];
  const float* enc = (const float*)d_in[1];
  const float* sa_wq = (const float*)d_in[4];
  const float* sa_bq = (const float*)d_in[5];
  const float* sa_wk = (const float*)d_in[6];
  const float* sa_bk = (const float*)d_in[7];
  const float* sa_wv = (const float*)d_in[8];
  const float* sa_bv = (const float*)d_in[9];
  const float* sa_wo = (const float*)d_in[10];
  const float* sa_bo = (const float*)d_in[11];
  const float* ca_wq = (const float*)d_in[12];
  const float* ca_bq = (const float*)d_in[13];
  const float* ca_wk = (const float*)d_in[14];
  const float* ca_bk = (const float*)d_in[15];
  const float* ca_wv = (const float*)d_in[16];
  const float* ca_bv = (const float*)d_in[17];
  const float* ca_wo = (const float*)d_in[18];
  const float* ca_bo = (const float*)d_in[19];
  const float* ffn_w1 = (const float*)d_in[20];
  const float* ffn_b1 = (const float*)d_in[21];
  const float* ffn_w2 = (const float*)d_in[22];
  const float* ffn_b2 = (const float*)d_in[23];
  const float* ln1_g = (const float*)d_in[24];
  const float* ln1_b = (const float*)d_in[25];
  const float* ln2_g = (const float*)d_in[26];
  const float* ln2_b = (const float*)d_in[27];
  const float* ln3_g = (const float*)d_in[28];
  const float* ln3_b = (const float*)d_in[29];

  // ---- workspace layout (~77 MiB) ----
  char* wsb = (char*)d_ws;
  // arena [0, 34603008): dec_bf (phase 1-2) / Opart+stats (attn) / MIDb (FFN)
  unsigned short* dec_bf = (unsigned short*)wsb;
  float* Opart = (float*)wsb;                        // 4*16*2048*64 f32 = 33.55MB
  float* Mst = (float*)(wsb + 33554432);
  float* Lst = (float*)(wsb + 34078720);
  unsigned short* MIDb = (unsigned short*)wsb;       // [4096][2048] bf16 (FFN phase)
  size_t off = 34603008;
  unsigned short* qkv_t = (unsigned short*)(wsb + off); off += 1572864;  // [1536][512]
  unsigned short* wo_t  = (unsigned short*)(wsb + off); off += 524288;
  unsigned short* cq_t  = (unsigned short*)(wsb + off); off += 524288;
  unsigned short* ckv_t = (unsigned short*)(wsb + off); off += 1048576;  // [1024][512]
  unsigned short* co_t  = (unsigned short*)(wsb + off); off += 524288;
  unsigned short* f1_t  = (unsigned short*)(wsb + off); off += 2097152;  // [2048][512]
  unsigned short* f2_t  = (unsigned short*)(wsb + off); off += 2097152;  // [512][2048]
  unsigned short* enc_bf = (unsigned short*)(wsb + off); off += 4194304;
  unsigned short* Qb  = (unsigned short*)(wsb + off); off += 4194304;
  unsigned short* Kb  = (unsigned short*)(wsb + off); off += 4194304;
  unsigned short* Vb  = (unsigned short*)(wsb + off); off += 4194304;
  unsigned short* AOb = (unsigned short*)(wsb + off); off += 4194304;
  unsigned short* X1b = (unsigned short*)(wsb + off); off += 4194304;
  unsigned short* X2b = (unsigned short*)(wsb + off); off += 4194304;
  float* R   = (float*)(wsb + off); off += 8388608;
  float* mu1 = (float*)(wsb + off); off += 16384;
  float* rs1 = (float*)(wsb + off); off += 16384;
  float* mu2 = (float*)(wsb + off); off += 16384;
  float* rs2 = (float*)(wsb + off); off += 16384;

  dim3 blk(256);
  const float QS = 0.125f * 1.44269504f;  // 1/sqrt(dk) * log2(e)  (exp2-domain softmax)

  // ---- prep ----
  WPack wp;
  wp.d[0] = {sa_wq, qkv_t, 512, 512};
  wp.d[1] = {sa_wk, qkv_t + 262144, 512, 512};
  wp.d[2] = {sa_wv, qkv_t + 524288, 512, 512};
  wp.d[3] = {sa_wo, wo_t, 512, 512};
  wp.d[4] = {ca_wq, cq_t, 512, 512};
  wp.d[5] = {ca_wk, ckv_t, 512, 512};
  wp.d[6] = {ca_wv, ckv_t + 262144, 512, 512};
  wp.d[7] = {ca_wo, co_t, 512, 512};
  wp.d[8] = {ffn_w1, f1_t, 512, 2048};
  wp.d[9] = {ffn_w2, f2_t, 2048, 512};
  wprep_kernel<<<dim3(1024, 10), blk, 0, stream>>>(wp);
  cast_kernel<<<1024, blk, 0, stream>>>(dec, dec_bf, 262144);
  cast_kernel<<<1024, blk, 0, stream>>>(enc, enc_bf, 262144);

  // ---- self-attention ----
  gemm_bf16<0, 128, 128><<<dim3(32, 12), blk, 0, stream>>>(dec_bf, qkv_t, sa_bq, sa_bk, sa_bv,
      nullptr, nullptr, nullptr, nullptr, nullptr, Qb, Kb, Vb, nullptr, MTOK, 1536, 512, QS);
  attn_bf16<true><<<dim3(16, 16, 4), blk, 0, stream>>>(Qb, Kb, Vb, Opart, Mst, Lst);
  combine_kernel<<<8192, blk, 0, stream>>>(Opart, Mst, Lst, AOb);
  gemm_bf16<1, 128, 64><<<dim3(32, 8), blk, 0, stream>>>(AOb, wo_t, sa_bo, nullptr, nullptr,
      dec, nullptr, nullptr, nullptr, nullptr, nullptr, nullptr, nullptr, R, MTOK, 512, 512, 1.f);
  ln_kernel<0><<<1024, blk, 0, stream>>>(R, ln1_g, ln1_b, nullptr, X1b, mu1, rs1);

  // ---- cross-attention ----
  gemm_bf16<0, 128, 64><<<dim3(32, 8), blk, 0, stream>>>(X1b, cq_t, ca_bq, nullptr, nullptr,
      nullptr, nullptr, nullptr, nullptr, nullptr, Qb, nullptr, nullptr, nullptr, MTOK, 512, 512, QS);
  gemm_bf16<0, 128, 128><<<dim3(32, 8), blk, 0, stream>>>(enc_bf, ckv_t, ca_bk, ca_bv, nullptr,
      nullptr, nullptr, nullptr, nullptr, nullptr, Kb, Vb, nullptr, nullptr, MTOK, 1024, 512, 1.f);
  attn_bf16<false><<<dim3(16, 16, 4), blk, 0, stream>>>(Qb, Kb, Vb, Opart, Mst, Lst);
  combine_kernel<<<8192, blk, 0, stream>>>(Opart, Mst, Lst, AOb);
  gemm_bf16<3, 128, 64><<<dim3(32, 8), blk, 0, stream>>>(AOb, co_t, ca_bo, nullptr, nullptr,
      R, mu1, rs1, ln1_g, ln1_b, nullptr, nullptr, nullptr, R, MTOK, 512, 512, 1.f);
  ln_kernel<0><<<1024, blk, 0, stream>>>(R, ln2_g, ln2_b, nullptr, X2b, mu2, rs2);

  // ---- FFN ----
  gemm_bf16<2, 128, 128><<<dim3(32, 16), blk, 0, stream>>>(X2b, f1_t, ffn_b1, nullptr, nullptr,
      nullptr, nullptr, nullptr, nullptr, nullptr, MIDb, nullptr, nullptr, nullptr, MTOK, 2048, 512, 1.f);
  gemm_bf16<3, 128, 64><<<dim3(32, 8), blk, 0, stream>>>(MIDb, f2_t, ffn_b2, nullptr, nullptr,
      R, mu2, rs2, ln2_g, ln2_b, nullptr, nullptr, nullptr, R, MTOK, 512, 2048, 1.f);
  ln_kernel<1><<<1024, blk, 0, stream>>>(R, ln3_g, ln3_b, (float*)d_out, nullptr, nullptr, nullptr);
}

// Round 8
// 409.240 us; speedup vs baseline: 1.0642x; 1.0642x over previous
//
#include <hip/hip_runtime.h>

// DecoderLayer (eval): SA(causal) -> +res -> LN1 -> CA -> +res -> LN2 -> FFN -> +res -> LN3
// Round-8: GEMM latency repair (round-7 counters: top GEMM 59us, MfmaUtil 5%,
// VALUBusy 8%, Occupancy 10% -> latency-bound at 1 block/CU, serial load->drain->compute).
//  - GEMM: 2-phase double-buffered prefetch (distinct __shared__ arrays As0/As1, Bs0/Bs1
//    so LDS alias analysis keeps ds_reads independent of in-flight global_load_lds),
//    BK=64, ONE barrier per K-step: STAGE(t+1, other) ; COMPUTE(cur) ; barrier.
//  - Attention/combine/LN unchanged from round 5 (defer-max, cvt_pk, exp2-domain).

#define D_MODEL 512
#define NHEAD 8
#define DK 64
#define SEQ 2048
#define MTOK 4096
#define DFF 2048

typedef __attribute__((ext_vector_type(8))) short bf16x8;
typedef __attribute__((ext_vector_type(4))) float f32x4;

#if __has_builtin(__builtin_amdgcn_exp2f)
#define EXP2(x) __builtin_amdgcn_exp2f(x)
#else
#define EXP2(x) exp2f(x)
#endif

__device__ __forceinline__ unsigned short f2bf(float x) {  // RTN-even
  unsigned u = __float_as_uint(x);
  u += 0x7FFF + ((u >> 16) & 1);
  return (unsigned short)(u >> 16);
}
__device__ __forceinline__ unsigned pack2(float a, float b) {
  return (unsigned)f2bf(a) | ((unsigned)f2bf(b) << 16);
}
__device__ __forceinline__ unsigned cvtpk(float lo, float hi) {  // RNE, 1 instr
  unsigned r;
  asm("v_cvt_pk_bf16_f32 %0, %1, %2" : "=v"(r) : "v"(lo), "v"(hi));
  return r;
}
__device__ __forceinline__ void load_lds16(const unsigned short* g, unsigned short* l) {
  __builtin_amdgcn_global_load_lds(
      (const __attribute__((address_space(1))) void*)g,
      (__attribute__((address_space(3))) void*)l, 16, 0, 0);
}

// ---------------------------------------------------------------------------
// Weight prep: fp32 [K][N] -> bf16 [N][K] (transpose + cast). Concat via dst offsets.
struct WDesc { const float* src; unsigned short* dst; int K; int N; };
struct WPack { WDesc d[10]; };

__global__ __launch_bounds__(256)
void wprep_kernel(WPack p) {
  const WDesc wd = p.d[blockIdx.y];
  const int ntx = wd.N >> 5;
  const int ntile = (wd.K >> 5) * ntx;
  if ((int)blockIdx.x >= ntile) return;
  const int n0 = (blockIdx.x % ntx) * 32;
  const int k0 = (blockIdx.x / ntx) * 32;
  __shared__ float T[32][33];
  const int tid = threadIdx.x;
  {
    const int r = tid >> 3, c4 = (tid & 7) * 4;
    float4 v = *(const float4*)(wd.src + (long)(k0 + r) * wd.N + n0 + c4);
    T[r][c4] = v.x; T[r][c4 + 1] = v.y; T[r][c4 + 2] = v.z; T[r][c4 + 3] = v.w;
  }
  __syncthreads();
  {
    const int n = tid >> 3, kq = (tid & 7) * 4;
    ushort4 o;
    o.x = f2bf(T[kq + 0][n]); o.y = f2bf(T[kq + 1][n]);
    o.z = f2bf(T[kq + 2][n]); o.w = f2bf(T[kq + 3][n]);
    *(ushort4*)(wd.dst + (long)(n0 + n) * wd.K + k0 + kq) = o;
  }
}

__global__ __launch_bounds__(256)
void cast_kernel(const float* __restrict__ s, unsigned short* __restrict__ d, int n8) {
  const int i = blockIdx.x * 256 + threadIdx.x;
  if (i >= n8) return;
  float4 a = *(const float4*)(s + (long)i * 8);
  float4 b = *(const float4*)(s + (long)i * 8 + 4);
  uint4 o;
  o.x = pack2(a.x, a.y); o.y = pack2(a.z, a.w);
  o.z = pack2(b.x, b.y); o.w = pack2(b.z, b.w);
  *(uint4*)(d + (long)i * 8) = o;
}

// ---------------------------------------------------------------------------
// bf16 MFMA GEMM, tile BM x BN, BK=64, 4 waves (2x2), wave tile (BM/2)x(BN/2).
// 2-phase double-buffered prefetch; one barrier per K-step.
// MODE 0: head-split bf16 out to o{0,1,2} by c>>9, bias b{0,1,2}[c&511], *scale0 on o0.
// MODE 1: fp32 out of = acc + b0[c] + res[r,c].
// MODE 2: bf16 out o0 = relu(acc + b0[c]).
// MODE 3: fp32 out of = acc + b0[c] + LN(res[r,c]; lnm,lnr,lng,lnbt)   (of may alias res).
template<int MODE, int BM, int BN>
__global__ __launch_bounds__(256)
void gemm_bf16(const unsigned short* __restrict__ A, const unsigned short* __restrict__ Wt,
               const float* __restrict__ b0, const float* __restrict__ b1,
               const float* __restrict__ b2, const float* res,
               const float* __restrict__ lnm, const float* __restrict__ lnr,
               const float* __restrict__ lng, const float* __restrict__ lnbt,
               unsigned short* __restrict__ o0, unsigned short* __restrict__ o1,
               unsigned short* __restrict__ o2, float* of,
               int M, int N, int K, float scale0) {
  constexpr int MF = BM / 32, NF = BN / 32;
  constexpr int AI = BM / 32;  // 16B chunks/thread for a BM x 64 tile
  constexpr int BI = BN / 32;
  // statically distinct buffers -> no false LDS aliasing between prefetch writes
  // and current-tile ds_reads (keeps the pipeline live).
  __shared__ unsigned short As0[BM * 64];
  __shared__ unsigned short As1[BM * 64];
  __shared__ unsigned short Bs0[BN * 64];
  __shared__ unsigned short Bs1[BN * 64];
  const int tid = threadIdx.x;
  const int w = tid >> 6, lane = tid & 63, g = lane >> 4, li = lane & 15;
  const int m0 = blockIdx.x * BM, n0 = blockIdx.y * BN;
  const int wm = w >> 1, wn = w & 1;

  f32x4 acc[MF][NF] = {};
  const unsigned short* Ap[AI];
  const unsigned short* Bp[BI];
#pragma unroll
  for (int i = 0; i < AI; i++) {
    const int idx = i * 256 + tid;
    Ap[i] = A + (long)(m0 + (idx % BM)) * K + (idx / BM) * 8;  // [kg8][row] layout
  }
#pragma unroll
  for (int i = 0; i < BI; i++) {
    const int idx = i * 256 + tid;
    Bp[i] = Wt + (long)(n0 + (idx % BN)) * K + (idx / BN) * 8;
  }
  const int nt = K >> 6;

#define G_STAGE(t, Ad, Bd)                                               \
  {                                                                      \
    _Pragma("unroll") for (int i = 0; i < AI; i++)                       \
        load_lds16(Ap[i] + (t) * 64, &Ad[(i * 256 + w * 64) * 8]);       \
    _Pragma("unroll") for (int i = 0; i < BI; i++)                       \
        load_lds16(Bp[i] + (t) * 64, &Bd[(i * 256 + w * 64) * 8]);       \
  }

#define G_COMP(Ad, Bd)                                                            \
  {                                                                               \
    _Pragma("unroll") for (int s = 0; s < 2; s++) {                               \
      bf16x8 af[MF], bfr[NF];                                                     \
      _Pragma("unroll") for (int mf = 0; mf < MF; mf++)                           \
          af[mf] = *(const bf16x8*)&Ad[((s * 4 + g) * BM + wm * (BM / 2) + mf * 16 + li) * 8]; \
      _Pragma("unroll") for (int nf = 0; nf < NF; nf++)                           \
          bfr[nf] = *(const bf16x8*)&Bd[((s * 4 + g) * BN + wn * (BN / 2) + nf * 16 + li) * 8]; \
      _Pragma("unroll") for (int mf = 0; mf < MF; mf++)                           \
          _Pragma("unroll") for (int nf = 0; nf < NF; nf++)                       \
              acc[mf][nf] = __builtin_amdgcn_mfma_f32_16x16x32_bf16(af[mf], bfr[nf], acc[mf][nf], 0, 0, 0); \
    }                                                                             \
  }

  G_STAGE(0, As0, Bs0);
  __syncthreads();  // compiler drains vmcnt before barrier -> tile 0 resident
  for (int t = 0; t < nt; t += 2) {
    if (t + 1 < nt) G_STAGE(t + 1, As1, Bs1);  // prefetch hides under compute
    G_COMP(As0, Bs0);
    __syncthreads();                           // drains prefetch; As0 reads done
    if (t + 1 < nt) {
      if (t + 2 < nt) G_STAGE(t + 2, As0, Bs0);
      G_COMP(As1, Bs1);
      __syncthreads();
    }
  }
#undef G_STAGE
#undef G_COMP

#pragma unroll
  for (int nf = 0; nf < NF; nf++) {
    const int c = n0 + wn * (BN / 2) + nf * 16 + li;
    float bias, scl = 1.f;
    unsigned short* hdst = nullptr;
    float lngv = 0.f, lnbv = 0.f;
    if constexpr (MODE == 0) {
      const int which = c >> 9;
      bias = (which == 0 ? b0 : (which == 1 ? b1 : b2))[c & 511];
      if (which == 0) scl = scale0;
      hdst = which == 0 ? o0 : (which == 1 ? o1 : o2);
    } else {
      bias = b0[c];
      if constexpr (MODE == 3) { lngv = lng[c]; lnbv = lnbt[c]; }
    }
#pragma unroll
    for (int mf = 0; mf < MF; mf++) {
#pragma unroll
      for (int j = 0; j < 4; j++) {
        const int r = m0 + wm * (BM / 2) + mf * 16 + g * 4 + j;
        float v = acc[mf][nf][j] + bias;
        if constexpr (MODE == 0) {
          v *= scl;
          const int b = r >> 11, s = r & (SEQ - 1), h = (c >> 6) & 7, d = c & 63;
          hdst[(((long)(b * NHEAD + h)) * SEQ + s) * DK + d] = f2bf(v);
        } else if constexpr (MODE == 1) {
          v += res[(long)r * N + c];
          of[(long)r * N + c] = v;
        } else if constexpr (MODE == 2) {
          o0[(long)r * N + c] = f2bf(fmaxf(v, 0.f));
        } else {
          const float xr = res[(long)r * N + c];
          v += (xr - lnm[r]) * lnr[r] * lngv + lnbv;
          of[(long)r * N + c] = v;
        }
      }
    }
  }
}

// ---------------------------------------------------------------------------
// Flash attention chunk, bf16 MFMA. Q pre-scaled by 0.125*log2e (exp2 domain).
// Grid (SEQ/128, B*NHEAD, 4). Writes unnormalized fp32 O + (m,l) per chunk.
template<bool CAUSAL>
__global__ __launch_bounds__(256)
void attn_bf16(const unsigned short* __restrict__ Qg, const unsigned short* __restrict__ Kg,
               const unsigned short* __restrict__ Vg, float* __restrict__ Opart,
               float* __restrict__ Mst, float* __restrict__ Lst) {
  __shared__ unsigned short SM[16384];   // 32KB
  unsigned short* const Qp = SM;         // [dg8][q128][8]  (dead after bq load)
  unsigned short* const Kp = SM + 8192;  // [dg8][k64][8]
  unsigned short* const Vt = SM + 12288; // [sg8][d64^swz][8]
  const int tid = threadIdx.x;
  const int w = tid >> 6, lane = tid & 63, g = lane >> 4, li = lane & 15;
  const int qb = blockIdx.x, bh = blockIdx.y, ck = blockIdx.z;
  const int q0 = qb * 128;
  const long base = (long)bh * SEQ * DK;
  unsigned short* const Pl = SM + w * 2048;  // aliases Qp region (per-wave)

#pragma unroll
  for (int i = 0; i < 4; i++) {
    const int idx = i * 256 + tid;
    const int dg = idx >> 7, q = idx & 127;
    load_lds16(Qg + base + (long)(q0 + q) * DK + dg * 8, &Qp[(i * 256 + w * 64) * 8]);
  }
  __syncthreads();
  bf16x8 bq[2][2];
#pragma unroll
  for (int qf = 0; qf < 2; qf++)
#pragma unroll
    for (int ks = 0; ks < 2; ks++)
      bq[qf][ks] = *(const bf16x8*)&Qp[((ks * 4 + g) * 128 + w * 32 + qf * 16 + li) * 8];

  f32x4 oacc[2][4] = {};
  float mrun[2] = {-1e30f, -1e30f};
  float denom[2] = {0.f, 0.f};

  const int vdg = tid >> 5;
  const int vs0 = (tid & 31) * 2;
  const int vsg = vs0 >> 3, vso = vs0 & 7;

  const int tbeg = CAUSAL ? ck : ck * 8;
  const int tend = CAUSAL ? (2 * qb + 2) : (ck * 8 + 8);
  const int tstep = CAUSAL ? 4 : 1;
  for (int t = tbeg; t < tend; t += tstep) {
    const int k0 = t * 64;
    __syncthreads();
#pragma unroll
    for (int i = 0; i < 2; i++) {
      const int idx = i * 256 + tid;
      const int dg = idx >> 6, kk = idx & 63;
      load_lds16(Kg + base + (long)(k0 + kk) * DK + dg * 8, &Kp[(i * 256 + w * 64) * 8]);
    }
    {
      const unsigned short* vsrc = Vg + base + (long)(k0 + vs0) * DK + vdg * 8;
      uint4 r0 = *(const uint4*)vsrc;
      uint4 r1 = *(const uint4*)(vsrc + DK);
      unsigned short u0[8], u1[8];
      *(uint4*)u0 = r0; *(uint4*)u1 = r1;
#pragma unroll
      for (int e = 0; e < 8; e++) {
        const int d = vdg * 8 + e;
        const int dsw = d ^ (vsg & 7);
        *(unsigned*)&Vt[(vsg * 64 + dsw) * 8 + vso] =
            (unsigned)u0[e] | ((unsigned)u1[e] << 16);
      }
    }
    __syncthreads();

    // S^T = K * Q^T (exp2 domain; Q pre-scaled)
    f32x4 sacc[4][2] = {};
#pragma unroll
    for (int ks = 0; ks < 2; ks++) {
#pragma unroll
      for (int kf = 0; kf < 4; kf++) {
        bf16x8 ka = *(const bf16x8*)&Kp[((ks * 4 + g) * 64 + kf * 16 + li) * 8];
#pragma unroll
        for (int qf = 0; qf < 2; qf++)
          sacc[kf][qf] = __builtin_amdgcn_mfma_f32_16x16x32_bf16(ka, bq[qf][ks], sacc[kf][qf], 0, 0, 0);
      }
    }
    if (CAUSAL && t >= 2 * qb) {
#pragma unroll
      for (int kf = 0; kf < 4; kf++)
#pragma unroll
        for (int qf = 0; qf < 2; qf++)
#pragma unroll
          for (int j = 0; j < 4; j++) {
            const int kg_ = k0 + kf * 16 + g * 4 + j;
            const int qg_ = q0 + w * 32 + qf * 16 + li;
            if (kg_ > qg_) sacc[kf][qf][j] = -1e30f;
          }
    }
    // tile max per q-row (replicated across the 4 g-groups of each li)
    float mx[2];
#pragma unroll
    for (int qf = 0; qf < 2; qf++) {
      float a = fmaxf(fmaxf(sacc[0][qf][0], sacc[0][qf][1]), fmaxf(sacc[0][qf][2], sacc[0][qf][3]));
      float b = fmaxf(fmaxf(sacc[1][qf][0], sacc[1][qf][1]), fmaxf(sacc[1][qf][2], sacc[1][qf][3]));
      float c = fmaxf(fmaxf(sacc[2][qf][0], sacc[2][qf][1]), fmaxf(sacc[2][qf][2], sacc[2][qf][3]));
      float d = fmaxf(fmaxf(sacc[3][qf][0], sacc[3][qf][1]), fmaxf(sacc[3][qf][2], sacc[3][qf][3]));
      float m_ = fmaxf(fmaxf(a, b), fmaxf(c, d));
      m_ = fmaxf(m_, __shfl_xor(m_, 16, 64));
      m_ = fmaxf(m_, __shfl_xor(m_, 32, 64));
      mx[qf] = m_;
    }
    // defer-max: only pay rescale when a row max grew by >8 (exp2-domain)
    const int full = !__all((mx[0] - mrun[0] <= 8.f) && (mx[1] - mrun[1] <= 8.f));
    float corrv[2] = {1.f, 1.f};
    if (full) {
#pragma unroll
      for (int qf = 0; qf < 2; qf++) {
        const float mn = fmaxf(mrun[qf], mx[qf]);
        corrv[qf] = EXP2(mrun[qf] - mn);
        mrun[qf] = mn;
      }
    }
#pragma unroll
    for (int qf = 0; qf < 2; qf++) {
      float ps = 0.f;
#pragma unroll
      for (int kf = 0; kf < 4; kf++)
#pragma unroll
        for (int j = 0; j < 4; j++) {
          const float p = EXP2(sacc[kf][qf][j] - mrun[qf]);
          sacc[kf][qf][j] = p;
          ps += p;
        }
      ps += __shfl_xor(ps, 16, 64);
      ps += __shfl_xor(ps, 32, 64);
      denom[qf] = denom[qf] * corrv[qf] + ps;
    }
    if (full) {
#pragma unroll
      for (int mf = 0; mf < 2; mf++)
#pragma unroll
        for (int j = 0; j < 4; j++) {
          const float cf = __shfl(corrv[mf], g * 4 + j, 64);
#pragma unroll
          for (int df = 0; df < 4; df++) oacc[mf][df][j] *= cf;
        }
    }
    // P -> LDS (bf16, v_cvt_pk)
#pragma unroll
    for (int kf = 0; kf < 4; kf++)
#pragma unroll
      for (int qf = 0; qf < 2; qf++) {
        uint2 pv;
        pv.x = cvtpk(sacc[kf][qf][0], sacc[kf][qf][1]);
        pv.y = cvtpk(sacc[kf][qf][2], sacc[kf][qf][3]);
        *(uint2*)&Pl[((kf * 2 + (g >> 1)) * 32 + qf * 16 + li) * 8 + (g & 1) * 4] = pv;
      }
#pragma unroll
    for (int ks2 = 0; ks2 < 2; ks2++) {
      const int sg = ks2 * 4 + g;
#pragma unroll
      for (int mf = 0; mf < 2; mf++) {
        bf16x8 pa = *(const bf16x8*)&Pl[(sg * 32 + mf * 16 + li) * 8];
#pragma unroll
        for (int df = 0; df < 4; df++) {
          bf16x8 vb = *(const bf16x8*)&Vt[(sg * 64 + ((df * 16 + li) ^ (sg & 7))) * 8];
          oacc[mf][df] = __builtin_amdgcn_mfma_f32_16x16x32_bf16(pa, vb, oacc[mf][df], 0, 0, 0);
        }
      }
    }
  }

  // unnormalized partial + stats
  const long pbase = (long)(ck * 16 + bh) * SEQ;
  if (g == 0) {
#pragma unroll
    for (int qf = 0; qf < 2; qf++) {
      const int q = q0 + w * 32 + qf * 16 + li;
      Mst[pbase + q] = mrun[qf];
      Lst[pbase + q] = denom[qf];
    }
  }
#pragma unroll
  for (int mf = 0; mf < 2; mf++)
#pragma unroll
    for (int j = 0; j < 4; j++) {
      const int q = q0 + w * 32 + mf * 16 + g * 4 + j;
      float* op = Opart + (pbase + q) * 64;
#pragma unroll
      for (int df = 0; df < 4; df++) op[df * 16 + li] = oacc[mf][df][j];
    }
}

// ---------------------------------------------------------------------------
// LSE combine over 4 chunks -> AOb bf16 [B,S,D_MODEL]. One wave per q row.
__global__ __launch_bounds__(256)
void combine_kernel(const float* __restrict__ Opart, const float* __restrict__ Mst,
                    const float* __restrict__ Lst, unsigned short* __restrict__ AOb) {
  const int row = blockIdx.x * 4 + (threadIdx.x >> 6);  // bh*SEQ + q
  const int lane = threadIdx.x & 63;
  const int bh = row >> 11, q = row & (SEQ - 1);
  float m[4], l[4], mstar = -1e30f;
#pragma unroll
  for (int c = 0; c < 4; c++) {
    m[c] = Mst[((long)c * 16 + bh) * SEQ + q];
    l[c] = Lst[((long)c * 16 + bh) * SEQ + q];
    mstar = fmaxf(mstar, m[c]);
  }
  float den = 0.f, o = 0.f;
#pragma unroll
  for (int c = 0; c < 4; c++) {
    const float wgt = EXP2(m[c] - mstar);
    den += wgt * l[c];
    o += wgt * Opart[(((long)c * 16 + bh) * SEQ + q) * 64 + lane];
  }
  const int b = bh >> 3, h = bh & 7;
  AOb[((long)(b * SEQ + q)) * D_MODEL + h * DK + lane] = f2bf(o / den);
}

// ---------------------------------------------------------------------------
// LayerNorm (512). V0: bf16 out + (mu,rstd) stats. V1: fp32 out.
template<int V>
__global__ __launch_bounds__(256)
void ln_kernel(const float* __restrict__ x, const float* __restrict__ gam,
               const float* __restrict__ bet, float* __restrict__ outf,
               unsigned short* __restrict__ outb, float* __restrict__ mu_s,
               float* __restrict__ rs_s) {
  const int row = blockIdx.x * 4 + (threadIdx.x >> 6);
  const int lane = threadIdx.x & 63;
  const float* xr = x + (long)row * D_MODEL;
  float4 v0 = *(const float4*)&xr[lane * 8];
  float4 v1 = *(const float4*)&xr[lane * 8 + 4];
  float xv[8] = {v0.x, v0.y, v0.z, v0.w, v1.x, v1.y, v1.z, v1.w};
  float s = 0.f, s2 = 0.f;
#pragma unroll
  for (int i = 0; i < 8; i++) { s += xv[i]; s2 = fmaf(xv[i], xv[i], s2); }
#pragma unroll
  for (int off = 32; off > 0; off >>= 1) {
    s += __shfl_xor(s, off, 64);
    s2 += __shfl_xor(s2, off, 64);
  }
  const float mu = s * (1.f / D_MODEL);
  const float var = fmaxf(s2 * (1.f / D_MODEL) - mu * mu, 0.f);
  const float rstd = rsqrtf(var + 1e-5f);
  float y[8];
#pragma unroll
  for (int i = 0; i < 8; i++) {
    const int c = lane * 8 + i;
    y[i] = (xv[i] - mu) * rstd * gam[c] + bet[c];
  }
  if constexpr (V == 0) {
    uint4 o;
    o.x = pack2(y[0], y[1]); o.y = pack2(y[2], y[3]);
    o.z = pack2(y[4], y[5]); o.w = pack2(y[6], y[7]);
    *(uint4*)(outb + (long)row * D_MODEL + lane * 8) = o;
    if (lane == 0) { mu_s[row] = mu; rs_s[row] = rstd; }
  } else {
    float* orow = outf + (long)row * D_MODEL + lane * 8;
    *(float4*)orow = make_float4(y[0], y[1], y[2], y[3]);
    *(float4*)(orow + 4) = make_float4(y[4], y[5], y[6], y[7]);
  }
}

// ---------------------------------------------------------------------------
extern "C" void kernel_launch(void* const* d_in, const int* in_sizes, int n_in,
                              void* d_out, int out_size, void* d_ws, size_t ws_size,
                              hipStream_t stream) {
  const float* dec = (const float*)d_in[0];
  const float* enc = (const float*)d_in[1];
  const float* sa_wq = (const float*)d_in[4];
  const float* sa_bq = (const float*)d_in[5];
  const float* sa_wk = (const float*)d_in[6];
  const float* sa_bk = (const float*)d_in[7];
  const float* sa_wv = (const float*)d_in[8];
  const float* sa_bv = (const float*)d_in[9];
  const float* sa_wo = (const float*)d_in[10];
  const float* sa_bo = (const float*)d_in[11];
  const float* ca_wq = (const float*)d_in[12];
  const float* ca_bq = (const float*)d_in[13];
  const float* ca_wk = (const float*)d_in[14];
  const float* ca_bk = (const float*)d_in[15];
  const float* ca_wv = (const float*)d_in[16];
  const float* ca_bv = (const float*)d_in[17];
  const float* ca_wo = (const float*)d_in[18];
  const float* ca_bo = (const float*)d_in[19];
  const float* ffn_w1 = (const float*)d_in[20];
  const float* ffn_b1 = (const float*)d_in[21];
  const float* ffn_w2 = (const float*)d_in[22];
  const float* ffn_b2 = (const float*)d_in[23];
  const float* ln1_g = (const float*)d_in[24];
  const float* ln1_b = (const float*)d_in[25];
  const float* ln2_g = (const float*)d_in[26];
  const float* ln2_b = (const float*)d_in[27];
  const float* ln3_g = (const float*)d_in[28];
  const float* ln3_b = (const float*)d_in[29];

  // ---- workspace layout (~77 MiB) ----
  char* wsb = (char*)d_ws;
  // arena [0, 34603008): dec_bf (phase 1-2) / Opart+stats (attn) / MIDb (FFN)
  unsigned short* dec_bf = (unsigned short*)wsb;
  float* Opart = (float*)wsb;                        // 4*16*2048*64 f32 = 33.55MB
  float* Mst = (float*)(wsb + 33554432);
  float* Lst = (float*)(wsb + 34078720);
  unsigned short* MIDb = (unsigned short*)wsb;       // [4096][2048] bf16 (FFN phase)
  size_t off = 34603008;
  unsigned short* qkv_t = (unsigned short*)(wsb + off); off += 1572864;  // [1536][512]
  unsigned short* wo_t  = (unsigned short*)(wsb + off); off += 524288;
  unsigned short* cq_t  = (unsigned short*)(wsb + off); off += 524288;
  unsigned short* ckv_t = (unsigned short*)(wsb + off); off += 1048576;  // [1024][512]
  unsigned short* co_t  = (unsigned short*)(wsb + off); off += 524288;
  unsigned short* f1_t  = (unsigned short*)(wsb + off); off += 2097152;  // [2048][512]
  unsigned short* f2_t  = (unsigned short*)(wsb + off); off += 2097152;  // [512][2048]
  unsigned short* enc_bf = (unsigned short*)(wsb + off); off += 4194304;
  unsigned short* Qb  = (unsigned short*)(wsb + off); off += 4194304;
  unsigned short* Kb  = (unsigned short*)(wsb + off); off += 4194304;
  unsigned short* Vb  = (unsigned short*)(wsb + off); off += 4194304;
  unsigned short* AOb = (unsigned short*)(wsb + off); off += 4194304;
  unsigned short* X1b = (unsigned short*)(wsb + off); off += 4194304;
  unsigned short* X2b = (unsigned short*)(wsb + off); off += 4194304;
  float* R   = (float*)(wsb + off); off += 8388608;
  float* mu1 = (float*)(wsb + off); off += 16384;
  float* rs1 = (float*)(wsb + off); off += 16384;
  float* mu2 = (float*)(wsb + off); off += 16384;
  float* rs2 = (float*)(wsb + off); off += 16384;

  dim3 blk(256);
  const float QS = 0.125f * 1.44269504f;  // 1/sqrt(dk) * log2(e)  (exp2-domain softmax)

  // ---- prep ----
  WPack wp;
  wp.d[0] = {sa_wq, qkv_t, 512, 512};
  wp.d[1] = {sa_wk, qkv_t + 262144, 512, 512};
  wp.d[2] = {sa_wv, qkv_t + 524288, 512, 512};
  wp.d[3] = {sa_wo, wo_t, 512, 512};
  wp.d[4] = {ca_wq, cq_t, 512, 512};
  wp.d[5] = {ca_wk, ckv_t, 512, 512};
  wp.d[6] = {ca_wv, ckv_t + 262144, 512, 512};
  wp.d[7] = {ca_wo, co_t, 512, 512};
  wp.d[8] = {ffn_w1, f1_t, 512, 2048};
  wp.d[9] = {ffn_w2, f2_t, 2048, 512};
  wprep_kernel<<<dim3(1024, 10), blk, 0, stream>>>(wp);
  cast_kernel<<<1024, blk, 0, stream>>>(dec, dec_bf, 262144);
  cast_kernel<<<1024, blk, 0, stream>>>(enc, enc_bf, 262144);

  // ---- self-attention ----
  gemm_bf16<0, 128, 128><<<dim3(32, 12), blk, 0, stream>>>(dec_bf, qkv_t, sa_bq, sa_bk, sa_bv,
      nullptr, nullptr, nullptr, nullptr, nullptr, Qb, Kb, Vb, nullptr, MTOK, 1536, 512, QS);
  attn_bf16<true><<<dim3(16, 16, 4), blk, 0, stream>>>(Qb, Kb, Vb, Opart, Mst, Lst);
  combine_kernel<<<8192, blk, 0, stream>>>(Opart, Mst, Lst, AOb);
  gemm_bf16<1, 128, 64><<<dim3(32, 8), blk, 0, stream>>>(AOb, wo_t, sa_bo, nullptr, nullptr,
      dec, nullptr, nullptr, nullptr, nullptr, nullptr, nullptr, nullptr, R, MTOK, 512, 512, 1.f);
  ln_kernel<0><<<1024, blk, 0, stream>>>(R, ln1_g, ln1_b, nullptr, X1b, mu1, rs1);

  // ---- cross-attention ----
  gemm_bf16<0, 128, 64><<<dim3(32, 8), blk, 0, stream>>>(X1b, cq_t, ca_bq, nullptr, nullptr,
      nullptr, nullptr, nullptr, nullptr, nullptr, Qb, nullptr, nullptr, nullptr, MTOK, 512, 512, QS);
  gemm_bf16<0, 128, 128><<<dim3(32, 8), blk, 0, stream>>>(enc_bf, ckv_t, ca_bk, ca_bv, nullptr,
      nullptr, nullptr, nullptr, nullptr, nullptr, Kb, Vb, nullptr, nullptr, MTOK, 1024, 512, 1.f);
  attn_bf16<false><<<dim3(16, 16, 4), blk, 0, stream>>>(Qb, Kb, Vb, Opart, Mst, Lst);
  combine_kernel<<<8192, blk, 0, stream>>>(Opart, Mst, Lst, AOb);
  gemm_bf16<3, 128, 64><<<dim3(32, 8), blk, 0, stream>>>(AOb, co_t, ca_bo, nullptr, nullptr,
      R, mu1, rs1, ln1_g, ln1_b, nullptr, nullptr, nullptr, R, MTOK, 512, 512, 1.f);
  ln_kernel<0><<<1024, blk, 0, stream>>>(R, ln2_g, ln2_b, nullptr, X2b, mu2, rs2);

  // ---- FFN ----
  gemm_bf16<2, 128, 128><<<dim3(32, 16), blk, 0, stream>>>(X2b, f1_t, ffn_b1, nullptr, nullptr,
      nullptr, nullptr, nullptr, nullptr, nullptr, MIDb, nullptr, nullptr, nullptr, MTOK, 2048, 512, 1.f);
  gemm_bf16<3, 128, 64><<<dim3(32, 8), blk, 0, stream>>>(MIDb, f2_t, ffn_b2, nullptr, nullptr,
      R, mu2, rs2, ln2_g, ln2_b, nullptr, nullptr, nullptr, R, MTOK, 512, 2048, 1.f);
  ln_kernel<1><<<1024, blk, 0, stream>>>(R, ln3_g, ln3_b, (float*)d_out, nullptr, nullptr, nullptr);
}